// Round 3
// baseline (328.903 us; speedup 1.0000x reference)
//
#include <hip/hip_runtime.h>
#include <math.h>

#define BB 16
#define QQ 900
#define CC 92
#define NP 32
#define TT (BB*NP)   // 512
#define NC 15        // columns per lane: 64*15 = 960 >= 900
#define QCHUNK 225   // 900/4 per cost-kernel block

// ---------------------------------------------------------------------------
// Cost build: grid (BB, 4) x 256. Block (b, c) handles q in [c*225, c*225+225).
// FP op order identical to the round-2 kernel (verified absmax = 0).
__launch_bounds__(256)
__global__ void cost_kernel(const float* __restrict__ logits,   // (B,Q,C)
                            const float* __restrict__ pboxes,   // (B,Q,4)
                            const int*   __restrict__ labels,   // (T,)
                            const float* __restrict__ tboxes,   // (T,4)
                            float* __restrict__ costws)         // (B,NP,Q)
{
    const int b   = blockIdx.x;
    const int ch  = blockIdx.y;
    const int q0  = ch * QCHUNK;
    const int tid = threadIdx.x;

    __shared__ float s_max[QCHUNK];
    __shared__ float s_sum[QCHUNK];

    const float* lg = logits + (size_t)b * QQ * CC;
    for (int r = tid; r < QCHUNK; r += 256) {
        const int q = q0 + r;
        const float4* row4 = (const float4*)(lg + q * CC);   // 92 = 23 float4, 16B-aligned
        float mx = -INFINITY;
        #pragma unroll
        for (int k = 0; k < 23; ++k) {
            float4 x = row4[k];
            mx = fmaxf(mx, x.x); mx = fmaxf(mx, x.y);
            mx = fmaxf(mx, x.z); mx = fmaxf(mx, x.w);
        }
        float s = 0.f;
        #pragma unroll
        for (int k = 0; k < 23; ++k) {
            float4 x = row4[k];
            s += expf(x.x - mx); s += expf(x.y - mx);
            s += expf(x.z - mx); s += expf(x.w - mx);
        }
        s_max[r] = mx;
        s_sum[r] = s;
    }
    __syncthreads();

    const float* pb = pboxes + (size_t)b * QQ * 4;
    const float* tb = tboxes + (size_t)b * NP * 4;
    const int*   lb = labels + b * NP;
    float* cw = costws + (size_t)b * NP * QQ;

    for (int e = tid; e < NP * QCHUNK; e += 256) {
        int t = e / QCHUNK;
        int r = e - t * QCHUNK;
        int q = q0 + r;
        float l    = lg[q * CC + lb[t]];
        float prob = expf(l - s_max[r]) / s_sum[r];
        float cclass = -prob;
        float p0 = pb[q*4+0], p1 = pb[q*4+1], p2 = pb[q*4+2], p3 = pb[q*4+3];
        float t0 = tb[t*4+0], t1 = tb[t*4+1], t2 = tb[t*4+2], t3 = tb[t*4+3];
        float cbbox = fabsf(p0-t0) + fabsf(p1-t1) + fabsf(p2-t2) + fabsf(p3-t3);
        float px1 = p0 - 0.5f*p2, py1 = p1 - 0.5f*p3;
        float px2 = p0 + 0.5f*p2, py2 = p1 + 0.5f*p3;
        float tx1 = t0 - 0.5f*t2, ty1 = t1 - 0.5f*t3;
        float tx2 = t0 + 0.5f*t2, ty2 = t1 + 0.5f*t3;
        float area1 = (px2-px1)*(py2-py1);
        float area2 = (tx2-tx1)*(ty2-ty1);
        float ltx = fmaxf(px1,tx1), lty = fmaxf(py1,ty1);
        float rbx = fminf(px2,tx2), rby = fminf(py2,ty2);
        float wx = fmaxf(rbx-ltx, 0.f), wy = fmaxf(rby-lty, 0.f);
        float inter = wx*wy;
        float uni = area1 + area2 - inter;
        float iou = inter / uni;
        float cx1 = fminf(px1,tx1), cy1 = fminf(py1,ty1);
        float cx2 = fmaxf(px2,tx2), cy2 = fmaxf(py2,ty2);
        float cwx = fmaxf(cx2-cx1, 0.f), cwy = fmaxf(cy2-cy1, 0.f);
        float areac = cwx*cwy;
        float giou = iou - (areac - uni) / areac;
        cw[t * QQ + q] = 5.f*cbbox + 1.f*cclass + 2.f*(-giou);
    }
}

// ---------------------------------------------------------------------------
// fp64 shuffle via two b32 shuffles (avoid relying on double overload)
__device__ __forceinline__ double shfl_xor_dbl(double x, int m) {
    long long l = __double_as_longlong(x);
    int lo = (int)(l & 0xffffffffLL);
    int hi = (int)(l >> 32);
    lo = __shfl_xor(lo, m, 64);
    hi = __shfl_xor(hi, m, 64);
    return __longlong_as_double(((long long)hi << 32) | (unsigned int)(unsigned)lo);
}

// ---------------------------------------------------------------------------
// Solver: ONE WAVE per batch block. Barrier-free inner loop — a wave is a
// single instruction stream and LDS ops per wave complete in order; volatile
// defeats compiler caching of cross-lane LDS values. Per-lane registers hold
// v/minv/used/rowidx for this lane's 15 columns (j = 1 + lane + 64k).
// Replicates the reference's quirky _lsa EXACTLY (transient mv = min(minv,cur),
// minv only accumulates -delta, delta may be negative, first-occurrence ties).
__launch_bounds__(64)
__global__ void solver_kernel(const float* __restrict__ costws,  // (B,NP,Q)
                              float* __restrict__ out)           // (Q,T)
{
    const int b    = blockIdx.x;
    const int lane = threadIdx.x;

    volatile __shared__ double s_u[NP + 1];
    volatile __shared__ int    s_p[QQ + 1];
    volatile __shared__ int    s_way[QQ + 1];

    for (int j = lane; j <= QQ; j += 64) { s_p[j] = 0; s_way[j] = 0; }
    if (lane <= NP) s_u[lane] = 0.0;

    double v[NC], minv[NC];
    int    rowidx[NC];
    #pragma unroll
    for (int k = 0; k < NC; ++k) v[k] = 0.0;

    const float* cbase = costws + (size_t)b * NP * QQ;
    __syncthreads();   // single wave: near-free; orders init vs phase loop

    for (int i = 1; i <= NP; ++i) {
        #pragma unroll
        for (int k = 0; k < NC; ++k) minv[k] = 1e18;
        unsigned usedmask = 0;
        if (lane == 0) s_p[0] = i;
        int j0 = 0;
        int i0 = i;            // p[j0=0] = i at phase start
        int final_j0 = 0;

        for (int guard = 0; guard < QQ + 2; ++guard) {
            // mark used[j0] (owner lane) and remember its row (p frozen in-phase)
            if (j0 != 0 && ((j0 - 1) & 63) == lane) {
                int k = (j0 - 1) >> 6;
                usedmask |= 1u << k;
                rowidx[k] = i0;
            }
            const double ui0  = s_u[i0];                 // LDS broadcast read
            const float* crow = cbase + (size_t)(i0 - 1) * QQ;

            // scan: transient mval = min(minv_old, cur); way on cur<minv_old;
            // minv itself NOT updated here (reference's .copy() quirk)
            double bv = 1e300;
            int    bi = 0x7fffffff;
            #pragma unroll
            for (int k = 0; k < NC; ++k) {
                int j = 1 + lane + (k << 6);
                if (j <= QQ && !(usedmask & (1u << k))) {
                    double cur  = (double)crow[j - 1] - ui0 - v[k];
                    double mval = minv[k];
                    if (cur < mval) { s_way[j] = j0; mval = cur; }
                    if (mval < bv)  { bv = mval; bi = j; }   // ascending j → first occurrence
                }
            }
            // butterfly argmin: every lane ends with global (delta, j1)
            #pragma unroll
            for (int off = 1; off < 64; off <<= 1) {
                double ov = shfl_xor_dbl(bv, off);
                int    oi = __shfl_xor(bi, off, 64);
                if (ov < bv || (ov == bv && oi < bi)) { bv = ov; bi = oi; }
            }
            const double delta = bv;    // may be negative (reference quirk)
            const int    j1    = bi;

            // dual update: u[p[used]] += delta (distinct rows, incl. j=0 col),
            // v[used] -= delta, minv[unused] -= delta
            if (lane == 0) s_u[i] = s_u[i] + delta;      // j=0 column → row i
            unsigned m = usedmask;
            while (m) {
                int k = __builtin_ctz(m); m &= m - 1;
                v[k] -= delta;
                s_u[rowidx[k]] = s_u[rowidx[k]] + delta; // distinct rows across lanes
            }
            #pragma unroll
            for (int k = 0; k < NC; ++k) {
                int j = 1 + lane + (k << 6);
                if (j <= QQ && !(usedmask & (1u << k))) minv[k] -= delta;
            }

            j0 = j1;
            int pj = s_p[j0];                            // volatile LDS read
            if (pj == 0) { final_j0 = j0; break; }
            i0 = pj;
        }

        // augmenting-path flip (reverse chain of visited j0s), lane 0 serial
        if (lane == 0) {
            int jj = final_j0;
            while (jj) { int jp = s_way[jj]; s_p[jj] = s_p[jp]; jj = jp; }
        }
        // in-order LDS per wave + volatile → next phase sees updated p
    }

    // write the full (900 x 32) output tile for this block (d_out is poisoned)
    for (int e = lane; e < QQ * NP; e += 64) {
        int q = e >> 5;              // e / 32
        int t = e & 31;              // e % 32
        out[(size_t)q * TT + b * NP + t] = (s_p[q + 1] == t + 1) ? 1.0f : 0.0f;
    }
}

// ---------------------------------------------------------------------------
extern "C" void kernel_launch(void* const* d_in, const int* in_sizes, int n_in,
                              void* d_out, int out_size, void* d_ws, size_t ws_size,
                              hipStream_t stream) {
    const float* logits = (const float*)d_in[0];   // (16,900,92)
    const float* pboxes = (const float*)d_in[1];   // (16,900,4)
    const int*   labels = (const int*)  d_in[2];   // (512,)
    const float* tboxes = (const float*)d_in[3];   // (512,4)
    float* out    = (float*)d_out;                 // (900,512) fp32
    float* costws = (float*)d_ws;                  // 16*32*900 floats = 1.84 MB

    cost_kernel<<<dim3(BB, 4), 256, 0, stream>>>(logits, pboxes, labels, tboxes, costws);
    solver_kernel<<<BB, 64, 0, stream>>>(costws, out);
}

// Round 4
// 238.774 us; speedup vs baseline: 1.3775x; 1.3775x over previous
//
#include <hip/hip_runtime.h>
#include <math.h>

#define BB 16
#define QQ 900
#define CC 92
#define NP 32
#define TT (BB*NP)   // 512
#define NC 15        // columns per lane: 64*15 = 960 >= 900
#define QCHUNK 225
#define RSTRIDE 960  // padded LDS row stride (floats) so k=14 loads stay in-bounds

// ---------------------------------------------------------------------------
// Cost build: grid (BB,4) x 256 — byte-identical FP order to round 2/3 (absmax=0).
__launch_bounds__(256)
__global__ void cost_kernel(const float* __restrict__ logits,
                            const float* __restrict__ pboxes,
                            const int*   __restrict__ labels,
                            const float* __restrict__ tboxes,
                            float* __restrict__ costws)
{
    const int b   = blockIdx.x;
    const int ch  = blockIdx.y;
    const int q0  = ch * QCHUNK;
    const int tid = threadIdx.x;

    __shared__ float s_max[QCHUNK];
    __shared__ float s_sum[QCHUNK];

    const float* lg = logits + (size_t)b * QQ * CC;
    for (int r = tid; r < QCHUNK; r += 256) {
        const int q = q0 + r;
        const float4* row4 = (const float4*)(lg + q * CC);
        float mx = -INFINITY;
        #pragma unroll
        for (int k = 0; k < 23; ++k) {
            float4 x = row4[k];
            mx = fmaxf(mx, x.x); mx = fmaxf(mx, x.y);
            mx = fmaxf(mx, x.z); mx = fmaxf(mx, x.w);
        }
        float s = 0.f;
        #pragma unroll
        for (int k = 0; k < 23; ++k) {
            float4 x = row4[k];
            s += expf(x.x - mx); s += expf(x.y - mx);
            s += expf(x.z - mx); s += expf(x.w - mx);
        }
        s_max[r] = mx;
        s_sum[r] = s;
    }
    __syncthreads();

    const float* pb = pboxes + (size_t)b * QQ * 4;
    const float* tb = tboxes + (size_t)b * NP * 4;
    const int*   lb = labels + b * NP;
    float* cw = costws + (size_t)b * NP * QQ;

    for (int e = tid; e < NP * QCHUNK; e += 256) {
        int t = e / QCHUNK;
        int r = e - t * QCHUNK;
        int q = q0 + r;
        float l    = lg[q * CC + lb[t]];
        float prob = expf(l - s_max[r]) / s_sum[r];
        float cclass = -prob;
        float p0 = pb[q*4+0], p1 = pb[q*4+1], p2 = pb[q*4+2], p3 = pb[q*4+3];
        float t0 = tb[t*4+0], t1 = tb[t*4+1], t2 = tb[t*4+2], t3 = tb[t*4+3];
        float cbbox = fabsf(p0-t0) + fabsf(p1-t1) + fabsf(p2-t2) + fabsf(p3-t3);
        float px1 = p0 - 0.5f*p2, py1 = p1 - 0.5f*p3;
        float px2 = p0 + 0.5f*p2, py2 = p1 + 0.5f*p3;
        float tx1 = t0 - 0.5f*t2, ty1 = t1 - 0.5f*t3;
        float tx2 = t0 + 0.5f*t2, ty2 = t1 + 0.5f*t3;
        float area1 = (px2-px1)*(py2-py1);
        float area2 = (tx2-tx1)*(ty2-ty1);
        float ltx = fmaxf(px1,tx1), lty = fmaxf(py1,ty1);
        float rbx = fminf(px2,tx2), rby = fminf(py2,ty2);
        float wx = fmaxf(rbx-ltx, 0.f), wy = fmaxf(rby-lty, 0.f);
        float inter = wx*wy;
        float uni = area1 + area2 - inter;
        float iou = inter / uni;
        float cx1 = fminf(px1,tx1), cy1 = fminf(py1,ty1);
        float cx2 = fmaxf(px2,tx2), cy2 = fmaxf(py2,ty2);
        float cwx = fmaxf(cx2-cx1, 0.f), cwy = fmaxf(cy2-cy1, 0.f);
        float areac = cwx*cwy;
        float giou = iou - (areac - uni) / areac;
        cw[t * QQ + q] = 5.f*cbbox + 1.f*cclass + 2.f*(-giou);
    }
}

// ---------------------------------------------------------------------------
__device__ __forceinline__ double shfl_xor_dbl(double x, int m) {
    long long l = __double_as_longlong(x);
    int lo = (int)(l & 0xffffffffLL);
    int hi = (int)(l >> 32);
    lo = __shfl_xor(lo, m, 64);
    hi = __shfl_xor(hi, m, 64);
    return __longlong_as_double(((long long)hi << 32) | (unsigned int)(unsigned)lo);
}

// Dynamic LDS partition (bytes)
#define OFF_COST 0
#define SZ_COST  (NP * RSTRIDE * 4)            // 122880
#define OFF_U    (OFF_COST + SZ_COST)          // 33 doubles -> 264
#define OFF_UPV  (OFF_U + 264)                 // 901 doubles -> 7208
#define OFF_D    (OFF_UPV + 7208)              // 34 doubles -> 272
#define OFF_P    (OFF_D + 272)                 // 901 ints -> 3604
#define OFF_PATH (OFF_P + 3604)                // 34 ints -> 136
#define DYN_BYTES (OFF_PATH + 136)             // 134364

// ---------------------------------------------------------------------------
// One wave per batch block. Exact reference semantics via the algebraic
// simplification: minv is always ~1e18 so mv==cur; way == visited-j0 chain;
// all u/v updates within a phase use phase-start values for scans, so the
// per-iteration updates are REPLAYED EXACTLY (same add order) at phase end.
__launch_bounds__(64)
__global__ void solver_kernel(const float* __restrict__ costws,
                              float* __restrict__ out)
{
    extern __shared__ char smem[];
    float*           s_cost = (float*)(smem + OFF_COST);      // [NP][RSTRIDE]
    volatile double* s_u    = (volatile double*)(smem + OFF_U);
    volatile double* s_upv  = (volatile double*)(smem + OFF_UPV); // u[p[j]]
    volatile double* s_d    = (volatile double*)(smem + OFF_D);   // deltas
    volatile int*    s_p    = (volatile int*)(smem + OFF_P);
    volatile int*    s_path = (volatile int*)(smem + OFF_PATH);   // visited j0s

    const int b    = blockIdx.x;
    const int lane = threadIdx.x;

    // ---- stage cost block into LDS (row stride padded to 960) -------------
    const float4* g4 = (const float4*)(costws + (size_t)b * NP * QQ);
    for (int e = lane; e < (NP * QQ) / 4; e += 64) {
        int row = e / (QQ / 4);            // 225 float4 per row
        int c4  = e - row * (QQ / 4);
        float4 x = g4[e];
        *((float4*)(s_cost + row * RSTRIDE) + c4) = x;
    }
    for (int j = lane; j <= QQ; j += 64) { s_p[j] = 0; s_upv[j] = 0.0; }
    if (lane <= NP) s_u[lane] = 0.0;

    double v[NC];
    #pragma unroll
    for (int k = 0; k < NC; ++k) v[k] = 0.0;

    __syncthreads();

    for (int i = 1; i <= NP; ++i) {
        unsigned usedmask = 0;
        if (lane == 0) { s_p[0] = i; s_path[0] = 0; }
        double ui0 = s_u[i];
        int i0 = i, prevj = 0, T = 0;

        for (int t = 1; ; ++t) {
            // mark previous j0 used (owner lane)
            if (prevj > 0 && ((prevj - 1) & 63) == lane)
                usedmask |= 1u << ((prevj - 1) >> 6);

            const float* crow = s_cost + (i0 - 1) * RSTRIDE;

            // scan: cur = ((c - u) - v); loads unconditional (padded row)
            double tv[16]; int ti[16];
            #pragma unroll
            for (int k = 0; k < NC; ++k) {
                int j = 1 + lane + (k << 6);
                float c = crow[j - 1];                 // in-bounds via RSTRIDE pad
                double cur = ((double)c - ui0) - v[k];
                bool valid = (j <= QQ) && !((usedmask >> k) & 1u);
                tv[k] = valid ? cur : 1e300;
                ti[k] = j;
            }
            tv[15] = 1e300; ti[15] = 0x7fffffff;
            // in-lane tree argmin (tie -> lower k == lower j)
            #pragma unroll
            for (int s = 8; s > 0; s >>= 1)
                #pragma unroll
                for (int k2 = 0; k2 < 8; ++k2)
                    if (k2 < s && tv[k2 + s] < tv[k2]) { tv[k2] = tv[k2 + s]; ti[k2] = ti[k2 + s]; }
            double bv = tv[0]; int bi = ti[0];

            // cross-lane butterfly argmin (tie -> lower j)
            #pragma unroll
            for (int off = 1; off < 64; off <<= 1) {
                double ov = shfl_xor_dbl(bv, off);
                int    oi = __shfl_xor(bi, off, 64);
                if (ov < bv || (ov == bv && oi < bi)) { bv = ov; bi = oi; }
            }
            const double delta = bv;
            const int    j1    = bi;

            if (lane == 0) { s_d[t] = delta; s_path[t] = j1; }
            int    pj   = s_p[j1];     // independent LDS broadcast reads
            double nupv = s_upv[j1];
            if (pj == 0) { T = t; break; }
            i0 = pj; ui0 = nupv; prevj = j1;
        }

        // ---- phase end: replay updates exactly (path j_1..j_T) -----------
        // (a) p shift: p_new[j_t] = p_old[j_{t-1}]; lockstep: all reads
        //     execute before the write instruction within the wave.
        int rt = 0, myj = 0;
        if (lane >= 1 && lane <= T) {
            myj = s_path[lane];
            int jprev = s_path[lane - 1];          // path[0] = 0
            rt = s_p[jprev];                       // p_old; also = row scanned at iter 'lane'
        }
        if (lane >= 1 && lane <= T) s_p[myj] = rt;
        // (b) u: row r_t receives += d_t, d_{t+1}, ..., d_T in that exact order
        if (lane >= 1 && lane <= T) {
            double uu = s_u[rt];
            for (int s = lane; s <= T; ++s) uu += s_d[s];
            s_u[rt] = uu;
            s_upv[myj] = uu;                       // p_new[j_t] == r_t
        }
        // (c) v: col j_t receives -= d_{t+1}, ..., d_T in that exact order
        for (int t2 = 1; t2 < T; ++t2) {
            int j = s_path[t2];
            if (((j - 1) & 63) == lane) {
                int k = (j - 1) >> 6;
                double vv = v[k];
                for (int s = t2 + 1; s <= T; ++s) vv -= s_d[s];
                v[k] = vv;
            }
        }
    }

    // ---- write full (900 x 32) tile for this block ------------------------
    for (int e = lane; e < QQ * NP; e += 64) {
        int q = e >> 5;
        int t = e & 31;
        out[(size_t)q * TT + b * NP + t] = (s_p[q + 1] == t + 1) ? 1.0f : 0.0f;
    }
}

// ---------------------------------------------------------------------------
extern "C" void kernel_launch(void* const* d_in, const int* in_sizes, int n_in,
                              void* d_out, int out_size, void* d_ws, size_t ws_size,
                              hipStream_t stream) {
    const float* logits = (const float*)d_in[0];
    const float* pboxes = (const float*)d_in[1];
    const int*   labels = (const int*)  d_in[2];
    const float* tboxes = (const float*)d_in[3];
    float* out    = (float*)d_out;
    float* costws = (float*)d_ws;

    // opt-in to >64KB dynamic LDS (gfx950: up to 160 KB per workgroup)
    (void)hipFuncSetAttribute((const void*)solver_kernel,
                              hipFuncAttributeMaxDynamicSharedMemorySize,
                              DYN_BYTES);

    cost_kernel<<<dim3(BB, 4), 256, 0, stream>>>(logits, pboxes, labels, tboxes, costws);
    solver_kernel<<<BB, 64, DYN_BYTES, stream>>>(costws, out);
}

// Round 5
// 227.198 us; speedup vs baseline: 1.4476x; 1.0509x over previous
//
#include <hip/hip_runtime.h>
#include <math.h>

#define BB 16
#define QQ 900
#define CC 92
#define NP 32
#define TT (BB*NP)   // 512
#define NC 15        // columns per lane: 64*15 = 960 >= 900
#define QCHUNK 225
#define RSTRIDE 960  // padded LDS row stride (floats)

// ---------------------------------------------------------------------------
// Cost build (unchanged from round 2/3/4 — verified absmax = 0).
__launch_bounds__(256)
__global__ void cost_kernel(const float* __restrict__ logits,
                            const float* __restrict__ pboxes,
                            const int*   __restrict__ labels,
                            const float* __restrict__ tboxes,
                            float* __restrict__ costws)
{
    const int b   = blockIdx.x;
    const int ch  = blockIdx.y;
    const int q0  = ch * QCHUNK;
    const int tid = threadIdx.x;

    __shared__ float s_max[QCHUNK];
    __shared__ float s_sum[QCHUNK];

    const float* lg = logits + (size_t)b * QQ * CC;
    for (int r = tid; r < QCHUNK; r += 256) {
        const int q = q0 + r;
        const float4* row4 = (const float4*)(lg + q * CC);
        float mx = -INFINITY;
        #pragma unroll
        for (int k = 0; k < 23; ++k) {
            float4 x = row4[k];
            mx = fmaxf(mx, x.x); mx = fmaxf(mx, x.y);
            mx = fmaxf(mx, x.z); mx = fmaxf(mx, x.w);
        }
        float s = 0.f;
        #pragma unroll
        for (int k = 0; k < 23; ++k) {
            float4 x = row4[k];
            s += expf(x.x - mx); s += expf(x.y - mx);
            s += expf(x.z - mx); s += expf(x.w - mx);
        }
        s_max[r] = mx;
        s_sum[r] = s;
    }
    __syncthreads();

    const float* pb = pboxes + (size_t)b * QQ * 4;
    const float* tb = tboxes + (size_t)b * NP * 4;
    const int*   lb = labels + b * NP;
    float* cw = costws + (size_t)b * NP * QQ;

    for (int e = tid; e < NP * QCHUNK; e += 256) {
        int t = e / QCHUNK;
        int r = e - t * QCHUNK;
        int q = q0 + r;
        float l    = lg[q * CC + lb[t]];
        float prob = expf(l - s_max[r]) / s_sum[r];
        float cclass = -prob;
        float p0 = pb[q*4+0], p1 = pb[q*4+1], p2 = pb[q*4+2], p3 = pb[q*4+3];
        float t0 = tb[t*4+0], t1 = tb[t*4+1], t2 = tb[t*4+2], t3 = tb[t*4+3];
        float cbbox = fabsf(p0-t0) + fabsf(p1-t1) + fabsf(p2-t2) + fabsf(p3-t3);
        float px1 = p0 - 0.5f*p2, py1 = p1 - 0.5f*p3;
        float px2 = p0 + 0.5f*p2, py2 = p1 + 0.5f*p3;
        float tx1 = t0 - 0.5f*t2, ty1 = t1 - 0.5f*t3;
        float tx2 = t0 + 0.5f*t2, ty2 = t1 + 0.5f*t3;
        float area1 = (px2-px1)*(py2-py1);
        float area2 = (tx2-tx1)*(ty2-ty1);
        float ltx = fmaxf(px1,tx1), lty = fmaxf(py1,ty1);
        float rbx = fminf(px2,tx2), rby = fminf(py2,ty2);
        float wx = fmaxf(rbx-ltx, 0.f), wy = fmaxf(rby-lty, 0.f);
        float inter = wx*wy;
        float uni = area1 + area2 - inter;
        float iou = inter / uni;
        float cx1 = fminf(px1,tx1), cy1 = fminf(py1,ty1);
        float cx2 = fmaxf(px2,tx2), cy2 = fmaxf(py2,ty2);
        float cwx = fmaxf(cx2-cx1, 0.f), cwy = fmaxf(cy2-cy1, 0.f);
        float areac = cwx*cwy;
        float giou = iou - (areac - uni) / areac;
        cw[t * QQ + q] = 5.f*cbbox + 1.f*cclass + 2.f*(-giou);
    }
}

// ---------------------------------------------------------------------------
__device__ __forceinline__ double mkdbl(int lo, int hi) {
    return __longlong_as_double(((long long)hi << 32) | (unsigned int)lo);
}

// DPP argmin step: combine (lo,hi,idx) with the DPP-moved neighbor triple.
// old = current value -> lanes without a valid source are a no-op combine.
#define DPP_ARGMIN(CTRL)                                                     \
    {                                                                        \
        int olo = __builtin_amdgcn_update_dpp(lo,  lo,  CTRL, 0xf, 0xf, false); \
        int ohi = __builtin_amdgcn_update_dpp(hi,  hi,  CTRL, 0xf, 0xf, false); \
        int oid = __builtin_amdgcn_update_dpp(idx, idx, CTRL, 0xf, 0xf, false); \
        double od = mkdbl(olo, ohi);                                         \
        double md = mkdbl(lo, hi);                                           \
        bool take = (od < md) || (od == md && oid < idx);                    \
        lo = take ? olo : lo; hi = take ? ohi : hi; idx = take ? oid : idx;  \
    }

// Dynamic LDS partition (bytes)
#define OFF_COST 0
#define SZ_COST  (NP * RSTRIDE * 4)        // 122880
#define OFF_U    (OFF_COST + SZ_COST)      // 33 dbl  -> 264
#define OFF_V    (OFF_U + 264)             // 901 dbl -> 7208
#define OFF_UPV  (OFF_V + 7208)            // 901 dbl -> 7208
#define OFF_D    (OFF_UPV + 7208)          // 40 dbl  -> 320
#define OFF_P    (OFF_D + 320)             // 901 int -> 3604
#define OFF_PATH (OFF_P + 3604)            // 40 int  -> 160
#define DYN_BYTES (OFF_PATH + 160)         // 141644

// ---------------------------------------------------------------------------
// One wave per batch block. Exact reference semantics (see round-4 notes):
// minv==cur algebraically; per-phase u/v frozen for scans; phase-end ordered
// replay. This round: DPP cross-lane argmin (no DS ops on the chain), v in
// LDS touched only at phase boundaries, register w[] with sentinel marking.
__launch_bounds__(64)
__global__ void solver_kernel(const float* __restrict__ costws,
                              float* __restrict__ out)
{
    extern __shared__ char smem[];
    float*           s_cost = (float*)(smem + OFF_COST);          // [NP][RSTRIDE]
    volatile double* s_u    = (volatile double*)(smem + OFF_U);
    volatile double* s_v    = (volatile double*)(smem + OFF_V);
    volatile double* s_upv  = (volatile double*)(smem + OFF_UPV); // u[p[j]]
    volatile double* s_d    = (volatile double*)(smem + OFF_D);   // deltas
    volatile int*    s_p    = (volatile int*)(smem + OFF_P);
    volatile int*    s_path = (volatile int*)(smem + OFF_PATH);   // visited j0s

    const int b    = blockIdx.x;
    const int lane = threadIdx.x;

    // ---- stage cost into LDS; zero the pad columns (NaN guard) ------------
    const float4* g4 = (const float4*)(costws + (size_t)b * NP * QQ);
    for (int e = lane; e < (NP * QQ) / 4; e += 64) {
        int row = e / (QQ / 4);
        int c4  = e - row * (QQ / 4);
        *((float4*)(s_cost + row * RSTRIDE) + c4) = g4[e];
    }
    for (int e = lane; e < NP * (RSTRIDE - QQ); e += 64) {
        int row = e / (RSTRIDE - QQ);
        int c   = e - row * (RSTRIDE - QQ);
        s_cost[row * RSTRIDE + QQ + c] = 0.f;
    }
    for (int j = lane; j <= QQ; j += 64) { s_p[j] = 0; s_upv[j] = 0.0; s_v[j] = 0.0; }
    if (lane <= NP) s_u[lane] = 0.0;
    __syncthreads();

    for (int i = 1; i <= NP; ++i) {
        // per-phase working copy of v (sentinel for out-of-range columns)
        double w[NC];
        #pragma unroll
        for (int k = 0; k < NC; ++k) {
            int j = 1 + lane + (k << 6);
            w[k] = (j <= QQ) ? s_v[j] : -1e30;
        }
        if (lane == 0) { s_p[0] = i; s_path[0] = 0; }
        double ui0 = s_u[i];
        int i0 = i, j1prev = 0, T = 0;

        for (int t = 1; t <= QQ + 1; ++t) {
            // mark previous j0 used: sentinel in w (static unroll, no dyn idx)
            if (j1prev != 0) {
                #pragma unroll
                for (int k = 0; k < NC; ++k)
                    w[k] = (1 + lane + (k << 6) == j1prev) ? -1e30 : w[k];
            }

            const float* crow = s_cost + (i0 - 1) * RSTRIDE;
            float cf[NC];
            #pragma unroll
            for (int k = 0; k < NC; ++k) cf[k] = crow[lane + (k << 6)];

            // cur = ((c - u) - v); used/out-of-range auto-lose via sentinel
            double tv[16]; int ti[16];
            #pragma unroll
            for (int k = 0; k < NC; ++k) {
                tv[k] = ((double)cf[k] - ui0) - w[k];
                ti[k] = 1 + lane + (k << 6);
            }
            tv[15] = 1e300; ti[15] = 0x7fffffff;
            // in-lane tree argmin (strict < keeps lower k == lower j on ties)
            #pragma unroll
            for (int s = 8; s > 0; s >>= 1)
                #pragma unroll
                for (int k2 = 0; k2 < 8; ++k2)
                    if (k2 < s && tv[k2 + s] < tv[k2]) { tv[k2] = tv[k2 + s]; ti[k2] = ti[k2 + s]; }

            // cross-lane DPP argmin -> lane 63 (VALU only, no DS ops)
            long long bl = __double_as_longlong(tv[0]);
            int lo  = (int)bl;
            int hi  = (int)(bl >> 32);
            int idx = ti[0];
            DPP_ARGMIN(0x111);   // row_shr:1
            DPP_ARGMIN(0x112);   // row_shr:2
            DPP_ARGMIN(0x114);   // row_shr:4
            DPP_ARGMIN(0x118);   // row_shr:8
            DPP_ARGMIN(0x142);   // row_bcast:15
            DPP_ARGMIN(0x143);   // row_bcast:31
            const int dlo = __builtin_amdgcn_readlane(lo, 63);
            const int dhi = __builtin_amdgcn_readlane(hi, 63);
            const int j1  = __builtin_amdgcn_readlane(idx, 63);
            const double delta = mkdbl(dlo, dhi);

            if (lane == 0) { s_d[t] = delta; s_path[t] = j1; }
            int    pj = s_p[j1];      // uniform LDS reads (overlap w/ marking)
            double nu = s_upv[j1];
            if (pj == 0) { T = t; break; }
            i0 = pj; ui0 = nu; j1prev = j1;
        }

        // ---- phase end: exact ordered replay (path j_1..j_T) --------------
        // (a) p shift: p_new[j_t] = p_old[j_{t-1}]; wave-lockstep read-then-write
        int rt = 0, myj = 0;
        if (lane >= 1 && lane <= T) {
            myj = s_path[lane];
            int jprev = s_path[lane - 1];
            rt = s_p[jprev];
        }
        if (lane >= 1 && lane <= T) s_p[myj] = rt;
        // (b) u: row r_t += d_t..d_T in order; upv[p_new[j_t]] = u_new[r_t]
        if (lane >= 1 && lane <= T) {
            double uu = s_u[rt];
            for (int s = lane; s <= T; ++s) uu += s_d[s];
            s_u[rt] = uu;
            s_upv[myj] = uu;
        }
        // (c) v: col j_t -= d_{t+1}..d_T in order (lane t2 owns col j_{t2})
        if (lane >= 1 && lane < T) {
            int j = s_path[lane];
            double vv = s_v[j];
            for (int s = lane + 1; s <= T; ++s) vv -= s_d[s];
            s_v[j] = vv;
        }
    }

    // ---- write full (900 x 32) tile for this block ------------------------
    for (int e = lane; e < QQ * NP; e += 64) {
        int q = e >> 5;
        int t = e & 31;
        out[(size_t)q * TT + b * NP + t] = (s_p[q + 1] == t + 1) ? 1.0f : 0.0f;
    }
}

// ---------------------------------------------------------------------------
extern "C" void kernel_launch(void* const* d_in, const int* in_sizes, int n_in,
                              void* d_out, int out_size, void* d_ws, size_t ws_size,
                              hipStream_t stream) {
    const float* logits = (const float*)d_in[0];
    const float* pboxes = (const float*)d_in[1];
    const int*   labels = (const int*)  d_in[2];
    const float* tboxes = (const float*)d_in[3];
    float* out    = (float*)d_out;
    float* costws = (float*)d_ws;

    (void)hipFuncSetAttribute((const void*)solver_kernel,
                              hipFuncAttributeMaxDynamicSharedMemorySize,
                              DYN_BYTES);

    cost_kernel<<<dim3(BB, 4), 256, 0, stream>>>(logits, pboxes, labels, tboxes, costws);
    solver_kernel<<<BB, 64, DYN_BYTES, stream>>>(costws, out);
}

// Round 6
// 219.487 us; speedup vs baseline: 1.4985x; 1.0351x over previous
//
#include <hip/hip_runtime.h>
#include <math.h>

#define BB 16
#define QQ 900
#define CC 92
#define NP 32
#define TT (BB*NP)   // 512
#define NC 15        // columns per lane: 64*15 = 960 >= 900
#define QCHUNK 225
#define RSTRIDE 960  // padded LDS row stride (floats)

// ---------------------------------------------------------------------------
// Cost build (unchanged since round 2 — verified absmax = 0).
__launch_bounds__(256)
__global__ void cost_kernel(const float* __restrict__ logits,
                            const float* __restrict__ pboxes,
                            const int*   __restrict__ labels,
                            const float* __restrict__ tboxes,
                            float* __restrict__ costws)
{
    const int b   = blockIdx.x;
    const int ch  = blockIdx.y;
    const int q0  = ch * QCHUNK;
    const int tid = threadIdx.x;

    __shared__ float s_max[QCHUNK];
    __shared__ float s_sum[QCHUNK];

    const float* lg = logits + (size_t)b * QQ * CC;
    for (int r = tid; r < QCHUNK; r += 256) {
        const int q = q0 + r;
        const float4* row4 = (const float4*)(lg + q * CC);
        float mx = -INFINITY;
        #pragma unroll
        for (int k = 0; k < 23; ++k) {
            float4 x = row4[k];
            mx = fmaxf(mx, x.x); mx = fmaxf(mx, x.y);
            mx = fmaxf(mx, x.z); mx = fmaxf(mx, x.w);
        }
        float s = 0.f;
        #pragma unroll
        for (int k = 0; k < 23; ++k) {
            float4 x = row4[k];
            s += expf(x.x - mx); s += expf(x.y - mx);
            s += expf(x.z - mx); s += expf(x.w - mx);
        }
        s_max[r] = mx;
        s_sum[r] = s;
    }
    __syncthreads();

    const float* pb = pboxes + (size_t)b * QQ * 4;
    const float* tb = tboxes + (size_t)b * NP * 4;
    const int*   lb = labels + b * NP;
    float* cw = costws + (size_t)b * NP * QQ;

    for (int e = tid; e < NP * QCHUNK; e += 256) {
        int t = e / QCHUNK;
        int r = e - t * QCHUNK;
        int q = q0 + r;
        float l    = lg[q * CC + lb[t]];
        float prob = expf(l - s_max[r]) / s_sum[r];
        float cclass = -prob;
        float p0 = pb[q*4+0], p1 = pb[q*4+1], p2 = pb[q*4+2], p3 = pb[q*4+3];
        float t0 = tb[t*4+0], t1 = tb[t*4+1], t2 = tb[t*4+2], t3 = tb[t*4+3];
        float cbbox = fabsf(p0-t0) + fabsf(p1-t1) + fabsf(p2-t2) + fabsf(p3-t3);
        float px1 = p0 - 0.5f*p2, py1 = p1 - 0.5f*p3;
        float px2 = p0 + 0.5f*p2, py2 = p1 + 0.5f*p3;
        float tx1 = t0 - 0.5f*t2, ty1 = t1 - 0.5f*t3;
        float tx2 = t0 + 0.5f*t2, ty2 = t1 + 0.5f*t3;
        float area1 = (px2-px1)*(py2-py1);
        float area2 = (tx2-tx1)*(ty2-ty1);
        float ltx = fmaxf(px1,tx1), lty = fmaxf(py1,ty1);
        float rbx = fminf(px2,tx2), rby = fminf(py2,ty2);
        float wx = fmaxf(rbx-ltx, 0.f), wy = fmaxf(rby-lty, 0.f);
        float inter = wx*wy;
        float uni = area1 + area2 - inter;
        float iou = inter / uni;
        float cx1 = fminf(px1,tx1), cy1 = fminf(py1,ty1);
        float cx2 = fmaxf(px2,tx2), cy2 = fmaxf(py2,ty2);
        float cwx = fmaxf(cx2-cx1, 0.f), cwy = fmaxf(cy2-cy1, 0.f);
        float areac = cwx*cwy;
        float giou = iou - (areac - uni) / areac;
        cw[t * QQ + q] = 5.f*cbbox + 1.f*cclass + 2.f*(-giou);
    }
}

// ---------------------------------------------------------------------------
__device__ __forceinline__ double mkdbl(int lo, int hi) {
    return __longlong_as_double(((long long)hi << 32) | (unsigned int)lo);
}
__device__ __forceinline__ double readlane_dbl(double x, int s) {
    long long l = __double_as_longlong(x);
    int lo = __builtin_amdgcn_readlane((int)l, s);
    int hi = __builtin_amdgcn_readlane((int)(l >> 32), s);
    return mkdbl(lo, hi);
}

// DPP min step on packed fp64 key `m` (3 instrs/stage: 2 dpp movs + v_min_f64;
// lanes without a DPP source keep their own value -> fmin no-op). Sequence
// row_shr:1/2/4/8 + row_bcast:15/31 leaves the global min in lane 63
// (verified on HW in round 5).
#define DPP_MIN(CTRL)                                                         \
    {                                                                         \
        long long _l = __double_as_longlong(m);                               \
        int _lo = (int)_l, _hi = (int)(_l >> 32);                             \
        int _olo = __builtin_amdgcn_update_dpp(_lo, _lo, CTRL, 0xf, 0xf, false); \
        int _ohi = __builtin_amdgcn_update_dpp(_hi, _hi, CTRL, 0xf, 0xf, false); \
        m = fmin(m, mkdbl(_olo, _ohi));                                       \
    }

// Dynamic LDS partition (bytes)
#define OFF_COST 0
#define SZ_COST  (NP * RSTRIDE * 4)        // 122880
#define OFF_U    (OFF_COST + SZ_COST)      // 33 dbl  -> 264
#define OFF_V    (OFF_U + 264)             // 901 dbl -> 7208
#define OFF_UPV  (OFF_V + 7208)            // 901 dbl -> 7208
#define OFF_P    (OFF_UPV + 7208)          // 901 int -> 3604
#define OFF_PATH (OFF_P + 3604)            // 40 int  -> 160
#define DYN_BYTES (OFF_PATH + 160)         // 141324

// ---------------------------------------------------------------------------
// One wave per batch block. Exact reference semantics:
//  * argmin over unused j of (c - u0[i0]) - v0[j]  ==  argmin of key(c - v0[j])
//    (scalar shift drops out; 10 low mantissa bits carry j, implementing
//    first-occurrence ties; perturbation ~1e-11 vs gaps ~1e-3)
//  * deltas recomputed at phase end in EXACT ref fp64 order (c - u0) - v0
//  * u/v replay keeps the reference's left-associated per-iteration add order
//    via readlane broadcasts of the delta sequence.
__launch_bounds__(64)
__global__ void solver_kernel(const float* __restrict__ costws,
                              float* __restrict__ out)
{
    extern __shared__ char smem[];
    float*           s_cost = (float*)(smem + OFF_COST);          // [NP][RSTRIDE]
    volatile double* s_u    = (volatile double*)(smem + OFF_U);
    volatile double* s_v    = (volatile double*)(smem + OFF_V);
    volatile double* s_upv  = (volatile double*)(smem + OFF_UPV); // u[p[j]]
    volatile int*    s_p    = (volatile int*)(smem + OFF_P);
    volatile int*    s_path = (volatile int*)(smem + OFF_PATH);   // visited j0s

    const int b    = blockIdx.x;
    const int lane = threadIdx.x;

    // ---- stage cost into LDS; zero pads (NaN guard for unconditional loads)
    const float4* g4 = (const float4*)(costws + (size_t)b * NP * QQ);
    for (int e = lane; e < (NP * QQ) / 4; e += 64) {
        int row = e / (QQ / 4);
        int c4  = e - row * (QQ / 4);
        *((float4*)(s_cost + row * RSTRIDE) + c4) = g4[e];
    }
    for (int e = lane; e < NP * (RSTRIDE - QQ); e += 64) {
        int row = e / (RSTRIDE - QQ);
        int c   = e - row * (RSTRIDE - QQ);
        s_cost[row * RSTRIDE + QQ + c] = 0.f;
    }
    for (int j = lane; j <= QQ; j += 64) { s_p[j] = 0; s_upv[j] = 0.0; s_v[j] = 0.0; }
    if (lane <= NP) s_u[lane] = 0.0;

    int jj[NC];
    #pragma unroll
    for (int k = 0; k < NC; ++k) jj[k] = 1 + lane + (k << 6);

    __syncthreads();

    for (int i = 1; i <= NP; ++i) {
        // per-phase frozen copy of v (sentinel -1e30 marks used/out-of-range:
        // key = c - (-1e30) ~ 1e30, never wins)
        double w[NC];
        #pragma unroll
        for (int k = 0; k < NC; ++k)
            w[k] = (jj[k] <= QQ) ? s_v[jj[k]] : -1e30;

        if (lane == 0) { s_p[0] = i; s_path[0] = 0; }
        int i0 = i, j1prev = 0, T = 0;

        for (int t = 1; t <= NP + 1; ++t) {
            // mark previous j0 used (static unroll, one column per iteration)
            if (j1prev) {
                #pragma unroll
                for (int k = 0; k < NC; ++k)
                    if (jj[k] == j1prev) w[k] = -1e30;
            }

            const float* crow = s_cost + (i0 - 1) * RSTRIDE;
            double key[NC];
            #pragma unroll
            for (int k = 0; k < NC; ++k) {
                float c = crow[lane + (k << 6)];
                double d = (double)c - w[k];
                long long bits = (__double_as_longlong(d) & ~1023LL) | (long long)jj[k];
                key[k] = __longlong_as_double(bits);
            }
            // 15-way in-lane min tree (pure v_min_f64, index rides in low bits)
            double a0 = fmin(key[0],  key[1]),  a1 = fmin(key[2],  key[3]);
            double a2 = fmin(key[4],  key[5]),  a3 = fmin(key[6],  key[7]);
            double a4 = fmin(key[8],  key[9]),  a5 = fmin(key[10], key[11]);
            double a6 = fmin(key[12], key[13]);
            double b0 = fmin(a0, a1), b1 = fmin(a2, a3);
            double b2 = fmin(a4, a5), b3 = fmin(a6, key[14]);
            double m  = fmin(fmin(b0, b1), fmin(b2, b3));

            DPP_MIN(0x111);  // row_shr:1
            DPP_MIN(0x112);  // row_shr:2
            DPP_MIN(0x114);  // row_shr:4
            DPP_MIN(0x118);  // row_shr:8
            DPP_MIN(0x142);  // row_bcast:15
            DPP_MIN(0x143);  // row_bcast:31

            int wlo = __builtin_amdgcn_readlane((int)__double_as_longlong(m), 63);
            int j1  = wlo & 1023;

            if (lane == 0) s_path[t] = j1;
            int pj = s_p[j1];                       // the only chained LDS read
            pj = __builtin_amdgcn_readfirstlane(pj);
            if (pj == 0) { T = t; break; }
            i0 = pj; j1prev = j1;
        }

        // ---- phase end: exact ordered replay (path j_1..j_T) --------------
        // (a) p shift: p_new[j_t] = p_old[j_{t-1}] (wave-lockstep read->write)
        int rt = 0, myj = 0;
        if (lane >= 1 && lane <= T) {
            myj = s_path[lane];
            int jp = s_path[lane - 1];              // path[0] = 0, s_p[0] = i
            rt = s_p[jp];                           // row scanned at iter t
        }
        if (lane >= 1 && lane <= T) s_p[myj] = rt;

        // deltas: delta_t = ((c[r_t][j_t] - u0[r_t]) - v0[j_t]) — exact order
        double mydelta = 0.0, uu = 0.0, vv = 0.0;
        if (lane >= 1 && lane <= T) {
            double cD = (double)s_cost[(rt - 1) * RSTRIDE + (myj - 1)];
            mydelta = (cD - s_u[rt]) - s_v[myj];
            uu = s_u[rt];
            vv = s_v[myj];
        }
        // (b) u[r_t] += d_t..d_T left-assoc; (c) v[j_t] -= d_{t+1}..d_T
        for (int s = 1; s <= T; ++s) {
            double ds = readlane_dbl(mydelta, s);
            if (lane >= 1 && lane <= s) uu += ds;
            if (lane >= 1 && lane <  s) vv -= ds;
        }
        if (lane >= 1 && lane <= T) {
            s_u[rt]    = uu;
            s_upv[myj] = uu;                        // p_new[j_t] == r_t
            s_v[myj]   = vv;                        // lane T writes back unchanged
        }
    }

    // ---- write full (900 x 32) tile for this block ------------------------
    for (int e = lane; e < QQ * NP; e += 64) {
        int q = e >> 5;
        int t = e & 31;
        out[(size_t)q * TT + b * NP + t] = (s_p[q + 1] == t + 1) ? 1.0f : 0.0f;
    }
}

// ---------------------------------------------------------------------------
extern "C" void kernel_launch(void* const* d_in, const int* in_sizes, int n_in,
                              void* d_out, int out_size, void* d_ws, size_t ws_size,
                              hipStream_t stream) {
    const float* logits = (const float*)d_in[0];
    const float* pboxes = (const float*)d_in[1];
    const int*   labels = (const int*)  d_in[2];
    const float* tboxes = (const float*)d_in[3];
    float* out    = (float*)d_out;
    float* costws = (float*)d_ws;

    (void)hipFuncSetAttribute((const void*)solver_kernel,
                              hipFuncAttributeMaxDynamicSharedMemorySize,
                              DYN_BYTES);

    cost_kernel<<<dim3(BB, 4), 256, 0, stream>>>(logits, pboxes, labels, tboxes, costws);
    solver_kernel<<<BB, 64, DYN_BYTES, stream>>>(costws, out);
}

// Round 8
// 168.636 us; speedup vs baseline: 1.9504x; 1.3015x over previous
//
#include <hip/hip_runtime.h>
#include <math.h>

#define BB 16
#define QQ 900
#define CC 92
#define NP 32
#define TT (BB*NP)     // 512
#define RSTRIDE 1024   // LDS cost row stride (floats): 64 lanes x 16 cols

// ---------------------------------------------------------------------------
__device__ __forceinline__ double mkdbl(int lo, int hi) {
    return __longlong_as_double(((long long)hi << 32) | (unsigned int)lo);
}
__device__ __forceinline__ double readlane_dbl(double x, int s) {
    long long l = __double_as_longlong(x);
    int lo = __builtin_amdgcn_readlane((int)l, s);
    int hi = __builtin_amdgcn_readlane((int)(l >> 32), s);
    return mkdbl(lo, hi);
}

// DPP min step on packed fp64 key `m` (2 dpp movs + v_min_f64). Sequence
// row_shr:1/2/4/8 + row_bcast:15/31 leaves the global min in lane 63
// (HW-verified in rounds 5/6, absmax=0).
#define DPP_MIN(CTRL)                                                         \
    {                                                                         \
        long long _l = __double_as_longlong(m);                               \
        int _lo = (int)_l, _hi = (int)(_l >> 32);                             \
        int _olo = __builtin_amdgcn_update_dpp(_lo, _lo, CTRL, 0xf, 0xf, false); \
        int _ohi = __builtin_amdgcn_update_dpp(_hi, _hi, CTRL, 0xf, 0xf, false); \
        m = fmin(m, mkdbl(_olo, _ohi));                                       \
    }

// Dynamic LDS partition (bytes)
#define OFF_COST 0
#define SZ_COST  (NP * RSTRIDE * 4)        // 131072
#define OFF_U    (OFF_COST + SZ_COST)      // 33 dbl  -> 264
#define OFF_V    (OFF_U + 264)             // 901 dbl -> 7208
#define OFF_P    (OFF_V + 7208)            // 901 int -> 3604
#define OFF_MAX  (OFF_P + 3604)            // 900 f   -> 3600
#define OFF_SUM  (OFF_MAX + 3600)          // 900 f   -> 3600
#define DYN_BYTES (OFF_SUM + 3600)         // 149348  (< 160 KiB)

// ---------------------------------------------------------------------------
// One block per batch b, 256 threads. Waves 0-3: softmax + cost build straight
// into LDS; wave 0 alone: the serial reference-_lsa walk (barrier-free, no
// in-loop LDS except 4x ds_read_b128 of the cost row); waves 0-3: epilogue.
//
// Exact reference semantics (established rounds 2-6, absmax=0):
//  * mv == cur algebraically (minv stays ~1e18) -> argmin over unused j of
//    (c - u0) - v0[j] == argmin of key(c - v0[j]); col index packed into the
//    key's low 11 bits gives first-occurrence tie-break.
//  * deltas recomputed at phase end in EXACT ref order ((c - u0) - v0);
//    u/v replayed with the reference's left-associated per-iteration order.
__launch_bounds__(256)
__global__ void matcher_kernel(const float* __restrict__ logits,   // (B,Q,C)
                               const float* __restrict__ pboxes,   // (B,Q,4)
                               const int*   __restrict__ labels,   // (T,)
                               const float* __restrict__ tboxes,   // (T,4)
                               float* __restrict__ out)            // (Q,T)
{
    extern __shared__ char smem[];
    float*           s_cost = (float*)(smem + OFF_COST);   // [NP][RSTRIDE]
    volatile double* s_u    = (volatile double*)(smem + OFF_U);
    volatile double* s_v    = (volatile double*)(smem + OFF_V);
    volatile int*    s_p    = (volatile int*)(smem + OFF_P);
    float*           s_max  = (float*)(smem + OFF_MAX);
    float*           s_sum  = (float*)(smem + OFF_SUM);

    const int b   = blockIdx.x;
    const int tid = threadIdx.x;

    // ---- softmax denominators (all 256 threads; FP order = rounds 3-6) ----
    const float* lg = logits + (size_t)b * QQ * CC;
    for (int q = tid; q < QQ; q += 256) {
        const float4* row4 = (const float4*)(lg + q * CC);   // 92 = 23 float4
        float mx = -INFINITY;
        #pragma unroll
        for (int k = 0; k < 23; ++k) {
            float4 x = row4[k];
            mx = fmaxf(mx, x.x); mx = fmaxf(mx, x.y);
            mx = fmaxf(mx, x.z); mx = fmaxf(mx, x.w);
        }
        float s = 0.f;
        #pragma unroll
        for (int k = 0; k < 23; ++k) {
            float4 x = row4[k];
            s += expf(x.x - mx); s += expf(x.y - mx);
            s += expf(x.z - mx); s += expf(x.w - mx);
        }
        s_max[q] = mx;
        s_sum[q] = s;
    }
    // init solver state
    for (int j = tid; j <= QQ; j += 256) { s_p[j] = 0; s_v[j] = 0.0; }
    if (tid <= NP) s_u[tid] = 0.0;
    __syncthreads();

    // ---- cost matrix -> LDS (FP order identical to rounds 2-6) ------------
    const float* pb = pboxes + (size_t)b * QQ * 4;
    const float* tb = tboxes + (size_t)b * NP * 4;
    const int*   lb = labels + b * NP;
    for (int e = tid; e < NP * QQ; e += 256) {
        int t = e / QQ;
        int q = e - t * QQ;
        float l    = lg[q * CC + lb[t]];
        float prob = expf(l - s_max[q]) / s_sum[q];
        float cclass = -prob;
        float p0 = pb[q*4+0], p1 = pb[q*4+1], p2 = pb[q*4+2], p3 = pb[q*4+3];
        float t0 = tb[t*4+0], t1 = tb[t*4+1], t2 = tb[t*4+2], t3 = tb[t*4+3];
        float cbbox = fabsf(p0-t0) + fabsf(p1-t1) + fabsf(p2-t2) + fabsf(p3-t3);
        float px1 = p0 - 0.5f*p2, py1 = p1 - 0.5f*p3;
        float px2 = p0 + 0.5f*p2, py2 = p1 + 0.5f*p3;
        float tx1 = t0 - 0.5f*t2, ty1 = t1 - 0.5f*t3;
        float tx2 = t0 + 0.5f*t2, ty2 = t1 + 0.5f*t3;
        float area1 = (px2-px1)*(py2-py1);
        float area2 = (tx2-tx1)*(ty2-ty1);
        float ltx = fmaxf(px1,tx1), lty = fmaxf(py1,ty1);
        float rbx = fminf(px2,tx2), rby = fminf(py2,ty2);
        float wx = fmaxf(rbx-ltx, 0.f), wy = fmaxf(rby-lty, 0.f);
        float inter = wx*wy;
        float uni = area1 + area2 - inter;
        float iou = inter / uni;
        float cx1 = fminf(px1,tx1), cy1 = fminf(py1,ty1);
        float cx2 = fmaxf(px2,tx2), cy2 = fmaxf(py2,ty2);
        float cwx = fmaxf(cx2-cx1, 0.f), cwy = fmaxf(cy2-cy1, 0.f);
        float areac = cwx*cwy;
        float giou = iou - (areac - uni) / areac;
        s_cost[t * RSTRIDE + q] = 5.f*cbbox + 1.f*cclass + 2.f*(-giou);
    }
    // zero pad columns 900..1023 (NaN guard for unconditional b128 loads)
    for (int e = tid; e < NP * (RSTRIDE - QQ); e += 256) {
        int row = e / (RSTRIDE - QQ);
        int c   = e - row * (RSTRIDE - QQ);
        s_cost[row * RSTRIDE + QQ + c] = 0.f;
    }
    __syncthreads();

    // ---- the serial walk: WAVE 0 ONLY, barrier-free -----------------------
    if (tid < 64) {
        const int lane = tid;
        int acol = 0;                       // lane r-1: column assigned to row r

        for (int i = 1; i <= NP; ++i) {
            // per-phase frozen copy of v (sentinel -1e30 for pads/used)
            double w[16];
            #pragma unroll
            for (int k = 0; k < 16; ++k) {
                int col = 4 * lane + ((k >> 2) << 8) + (k & 3) + 1;
                w[k] = (col <= QQ) ? s_v[col] : -1e30;
            }

            int i0 = i, j1prev = 0, T = 0;
            int path_reg = 1, row_reg = 1;

            for (int t = 1; t <= NP + 1; ++t) {
                // mark previous winner used (one slot flips; static unroll)
                if (j1prev) {
                    #pragma unroll
                    for (int k = 0; k < 16; ++k) {
                        int col = 4 * lane + ((k >> 2) << 8) + (k & 3) + 1;
                        if (col == j1prev) w[k] = -1e30;
                    }
                }
                // writelane(i0, t): i0 is wave-uniform -> predicated move
                if (lane == t) row_reg = i0;

                // 4x ds_read_b128 of the cost row
                const float4* crow4 = (const float4*)(s_cost + (i0 - 1) * RSTRIDE);
                float4 cf[4];
                #pragma unroll
                for (int k = 0; k < 4; ++k) cf[k] = crow4[lane + (k << 6)];

                // keys: (c - v0[j]) with col in low 11 bits (first-occurrence ties)
                double key[16];
                #pragma unroll
                for (int k = 0; k < 4; ++k) {
                    const float* cp = (const float*)&cf[k];
                    #pragma unroll
                    for (int e2 = 0; e2 < 4; ++e2) {
                        int col = 4 * lane + (k << 8) + e2 + 1;
                        double d = (double)cp[e2] - w[4 * k + e2];
                        long long bits =
                            (__double_as_longlong(d) & ~2047LL) | (long long)col;
                        key[4 * k + e2] = __longlong_as_double(bits);
                    }
                }
                // in-lane 16-way min tree (pure v_min_f64)
                double a0 = fmin(key[0], key[1]),   a1 = fmin(key[2], key[3]);
                double a2 = fmin(key[4], key[5]),   a3 = fmin(key[6], key[7]);
                double a4 = fmin(key[8], key[9]),   a5 = fmin(key[10], key[11]);
                double a6 = fmin(key[12], key[13]), a7 = fmin(key[14], key[15]);
                double b0 = fmin(a0, a1), b1 = fmin(a2, a3);
                double b2 = fmin(a4, a5), b3 = fmin(a6, a7);
                double m  = fmin(fmin(b0, b1), fmin(b2, b3));

                DPP_MIN(0x111);  // row_shr:1
                DPP_MIN(0x112);  // row_shr:2
                DPP_MIN(0x114);  // row_shr:4
                DPP_MIN(0x118);  // row_shr:8
                DPP_MIN(0x142);  // row_bcast:15
                DPP_MIN(0x143);  // row_bcast:31

                int wlo = __builtin_amdgcn_readlane((int)__double_as_longlong(m), 63);
                int j1  = wlo & 2047;

                // writelane(j1, t): j1 is wave-uniform -> predicated move
                if (lane == t) path_reg = j1;

                // p[j1] via ballot over register-resident assignment map
                unsigned long long mask = __ballot(acol == j1);
                if (mask == 0) { T = t; break; }
                i0 = (int)__builtin_ctzll(mask) + 1;
                j1prev = j1;
            }

            // ---- phase end: exact ordered replay (lanes 1..T hold r_t, j_t)
            const int  rt  = row_reg;
            const int  myj = path_reg;
            const bool act = (lane >= 1 && lane <= T);
            double mydelta = 0.0, uu = 0.0, vv = 0.0;
            if (act) {
                double cD = (double)s_cost[(rt - 1) * RSTRIDE + (myj - 1)];
                mydelta = (cD - s_u[rt]) - s_v[myj];   // exact ref op order
                uu = s_u[rt];
                vv = s_v[myj];
            }
            for (int s = 1; s <= T; ++s) {
                double ds = readlane_dbl(mydelta, s);
                int    js = __builtin_amdgcn_readlane(path_reg, s);
                int    rs = __builtin_amdgcn_readlane(row_reg, s);
                if (lane >= 1 && lane <= s) uu += ds;   // u[r_t] += d_t..d_T
                if (lane >= 1 && lane <  s) vv -= ds;   // v[j_t] -= d_{t+1}..d_T
                if (rs == lane + 1) acol = js;          // row r_s now on col j_s
            }
            if (act) {
                s_u[rt]  = uu;
                s_v[myj] = vv;
                s_p[myj] = rt;
            }
        }
    }
    __syncthreads();

    // ---- epilogue: full (900 x 32) tile, float4 stores (all 256 threads) --
    for (int e = tid; e < QQ * 8; e += 256) {
        int q = e >> 3;
        int f = e & 7;
        int pq = s_p[q + 1];
        int base = 4 * f;
        float4 o;
        o.x = (pq == base + 1) ? 1.f : 0.f;
        o.y = (pq == base + 2) ? 1.f : 0.f;
        o.z = (pq == base + 3) ? 1.f : 0.f;
        o.w = (pq == base + 4) ? 1.f : 0.f;
        ((float4*)(out + (size_t)q * TT + b * NP))[f] = o;
    }
}

// ---------------------------------------------------------------------------
extern "C" void kernel_launch(void* const* d_in, const int* in_sizes, int n_in,
                              void* d_out, int out_size, void* d_ws, size_t ws_size,
                              hipStream_t stream) {
    const float* logits = (const float*)d_in[0];   // (16,900,92)
    const float* pboxes = (const float*)d_in[1];   // (16,900,4)
    const int*   labels = (const int*)  d_in[2];   // (512,)
    const float* tboxes = (const float*)d_in[3];   // (512,4)
    float* out = (float*)d_out;                    // (900,512) fp32

    (void)hipFuncSetAttribute((const void*)matcher_kernel,
                              hipFuncAttributeMaxDynamicSharedMemorySize,
                              DYN_BYTES);

    matcher_kernel<<<BB, 256, DYN_BYTES, stream>>>(logits, pboxes, labels,
                                                   tboxes, out);
}